// Round 1
// 206.060 us; speedup vs baseline: 1.0675x; 1.0675x over previous
//
#include <hip/hip_runtime.h>
#include <math.h>

#define HDIM 768
#define RDIM 64
#define NEXP 8
#define NTOK 16384

typedef _Float16 half8 __attribute__((ext_vector_type(8)));
typedef float float4_t __attribute__((ext_vector_type(4)));

__device__ __forceinline__ float gelu_exact(float v) {
    return 0.5f * v * (1.0f + erff(v * 0.70710678118654752440f));
}

// ---------------------------------------------------------------------------
// prep: weight transposes/casts. (unchanged)
//   w1t[e][r][k]  = (f16)w1[e][k][r]
//   w2t[e][n][k]  = (f16)w2[e][k][n]
//   enc_hi/lo[r][k] = split-f16 of enc_w[k][r]
// ---------------------------------------------------------------------------
__global__ __launch_bounds__(256) void prep_kernel(
    const float* __restrict__ w1, const float* __restrict__ w2,
    const float* __restrict__ enc_w,
    _Float16* __restrict__ w1t, _Float16* __restrict__ w2t,
    _Float16* __restrict__ enc_hi, _Float16* __restrict__ enc_lo)
{
    const int wid = blockIdx.x * 4 + (threadIdx.x >> 6);
    const int lane = threadIdx.x & 63;
    if (wid < 768) {
        const int e = wid / 96, k0 = (wid % 96) * 8;
        half8 o;
        #pragma unroll
        for (int j = 0; j < 8; j++)
            o[j] = (_Float16)w1[((size_t)(e * HDIM + k0 + j)) * RDIM + lane];
        *(half8*)(w1t + ((size_t)(e * RDIM + lane)) * HDIM + k0) = o;
    } else if (wid < 1536) {
        const int id = wid - 768;
        const int e = id / 96, rem = id % 96;
        const int n = (rem >> 3) * 64 + lane, k0 = (rem & 7) * 8;
        half8 o;
        #pragma unroll
        for (int j = 0; j < 8; j++)
            o[j] = (_Float16)w2[((size_t)(e * RDIM + k0 + j)) * HDIM + n];
        *(half8*)(w2t + ((size_t)(e * HDIM + n)) * RDIM + k0) = o;
    } else if (wid < 1632) {
        const int k0 = (wid - 1536) * 8;
        half8 hi, lo;
        #pragma unroll
        for (int j = 0; j < 8; j++) {
            float v = enc_w[(size_t)(k0 + j) * RDIM + lane];
            _Float16 h = (_Float16)v;
            hi[j] = h;
            lo[j] = (_Float16)(v - (float)h);
        }
        *(half8*)(enc_hi + (size_t)lane * HDIM + k0) = hi;
        *(half8*)(enc_lo + (size_t)lane * HDIM + k0) = lo;
    }
}

// ---------------------------------------------------------------------------
// router v2: K-split across the 4 waves of a block.
// 16 tokens/block, grid = NTOK/16 = 1024 blocks (4 blocks/CU -> 16 waves/CU),
// vs v1's 256 blocks @ 1 wave/SIMD which was pure latency exposure.
// Wave w accumulates K in [w*192, w*192+192) (6 MFMA steps, hi/lo split),
// partials reduced through LDS, then the proven fp32 softmax/argmax epilogue
// runs on 16 tokens (tid<128).
// ---------------------------------------------------------------------------
__global__ __launch_bounds__(256) void router_kernel(
    const float* __restrict__ x,
    const _Float16* __restrict__ enc_hi, const _Float16* __restrict__ enc_lo,
    const float* __restrict__ enc_b, const float* __restrict__ sw_w,
    const float* __restrict__ sw_b, float* __restrict__ pmax,
    int* __restrict__ counts, int* __restrict__ lists)
{
    __shared__ __align__(16) float part[4][16][68];
    __shared__ __align__(16) float sws[512];
    __shared__ int lcnt[NEXP], gbase[NEXP];

    const int tid = threadIdx.x;
    const int tok0 = blockIdx.x * 16;
    const int wv = tid >> 6, lane = tid & 63;
    const int q = lane >> 4, c = lane & 15;

    if (tid < 128) ((float4*)sws)[tid] = ((const float4*)sw_w)[tid];
    if (tid < NEXP) lcnt[tid] = 0;

    // ---- phase 1: partial xenc over this wave's K-chunk ----
    const float* xrow = x + (size_t)(tok0 + c) * HDIM + wv * 192;
    const _Float16* ebase_hi = enc_hi + (size_t)c * HDIM + wv * 192 + q * 8;
    const _Float16* ebase_lo = enc_lo + (size_t)c * HDIM + wv * 192 + q * 8;

    float4_t acc[4] = {{0,0,0,0},{0,0,0,0},{0,0,0,0},{0,0,0,0}};
    #pragma unroll
    for (int it = 0; it < 6; it++) {
        const int k0 = it * 32;
        float4 u0 = *(const float4*)(xrow + k0 + q * 8);
        float4 u1 = *(const float4*)(xrow + k0 + q * 8 + 4);
        float u[8] = {u0.x, u0.y, u0.z, u0.w, u1.x, u1.y, u1.z, u1.w};
        half8 ah, al;
        #pragma unroll
        for (int j = 0; j < 8; j++) {
            _Float16 hv = (_Float16)u[j];
            ah[j] = hv;
            al[j] = (_Float16)(u[j] - (float)hv);
        }
        #pragma unroll
        for (int nf = 0; nf < 4; nf++) {
            half8 bh = *(const half8*)(ebase_hi + (size_t)nf * 16 * HDIM + k0);
            half8 bl = *(const half8*)(ebase_lo + (size_t)nf * 16 * HDIM + k0);
            acc[nf] = __builtin_amdgcn_mfma_f32_16x16x32_f16(ah, bh, acc[nf], 0, 0, 0);
            acc[nf] = __builtin_amdgcn_mfma_f32_16x16x32_f16(ah, bl, acc[nf], 0, 0, 0);
            acc[nf] = __builtin_amdgcn_mfma_f32_16x16x32_f16(al, bh, acc[nf], 0, 0, 0);
        }
    }

    // ---- stash per-wave partials (2-way-aliased banks = free) ----
    #pragma unroll
    for (int nf = 0; nf < 4; nf++)
        #pragma unroll
        for (int i = 0; i < 4; i++)
            part[wv][q * 4 + i][nf * 16 + c] = acc[nf][i];
    __syncthreads();

    // ---- reduce 4 K-chunks + enc_b; xe lives in part[0] ----
    #pragma unroll
    for (int j = 0; j < 4; j++) {
        const int idx = tid + 256 * j;
        const int row = idx >> 6, r = idx & 63;
        float v = part[0][row][r] + part[1][row][r] + part[2][row][r]
                + part[3][row][r] + enc_b[r];
        part[0][row][r] = v;
    }
    __syncthreads();

    // ---- phase 3: logits/softmax/argmax on 16 tokens (tid<128) ----
    int am_s = -1, lp_s = 0;
    if (tid < 128) {
        const int e = tid & 7;
        const int t = tid >> 3;   // 0..15
        float logit = sw_b[e];
        #pragma unroll 16
        for (int r = 0; r < RDIM; r++)
            logit += part[0][t][r] * sws[r * NEXP + e];
        float m = logit; int am = e;
        #pragma unroll
        for (int d = 4; d >= 1; d >>= 1) {
            float om = __shfl_xor(m, d, 8);
            int oam  = __shfl_xor(am, d, 8);
            if (om > m || (om == m && oam < am)) { m = om; am = oam; }
        }
        float s = expf(logit - m);
        #pragma unroll
        for (int d = 1; d <= 4; d <<= 1) s += __shfl_xor(s, d, 8);
        if (e == 0) {
            pmax[tok0 + t] = 1.0f / s;
            am_s = am;
            lp_s = atomicAdd(&lcnt[am], 1);
        }
    }
    __syncthreads();
    if (tid < NEXP) gbase[tid] = atomicAdd(&counts[tid * 32], lcnt[tid]);
    __syncthreads();
    if (am_s >= 0)
        lists[am_s * NTOK + gbase[am_s] + lp_s] = tok0 + (tid >> 3);
}

// ---------------------------------------------------------------------------
// mm1 v2: same K-split-by-4 fix. One 16-token strip per block iteration,
// 4 waves each do K in [w*192, w*192+192), LDS-reduce, gelu, store f16 h.
// Grid (8, 128): all 4 waves of every working block are busy (v1 had 3/4 of
// its waves idle -> 1 working wave/SIMD).
// ---------------------------------------------------------------------------
__global__ __launch_bounds__(256) void mm1_kernel(
    const float* __restrict__ x, const _Float16* __restrict__ w1t,
    const float* __restrict__ b1, const int* __restrict__ counts,
    const int* __restrict__ lists, _Float16* __restrict__ h)
{
    __shared__ __align__(16) float part[4][16][68];

    const int e = blockIdx.x;
    const int cnt = counts[e * 32];
    const int tid = threadIdx.x;
    const int wv = tid >> 6, lane = tid & 63;
    const int q = lane >> 4, c = lane & 15;

    for (int st = blockIdx.y; st * 16 < cnt; st += gridDim.y) {
        const int base = st * 16;
        const int nt = cnt - base;
        const int tA = lists[e * NTOK + base + min(c, nt - 1)];
        const float* xrow = x + (size_t)tA * HDIM + wv * 192;
        const _Float16* wbase = w1t + ((size_t)(e * RDIM + c)) * HDIM + wv * 192 + q * 8;

        float4_t acc[4] = {{0,0,0,0},{0,0,0,0},{0,0,0,0},{0,0,0,0}};
        #pragma unroll
        for (int it = 0; it < 6; it++) {
            const int k0 = it * 32;
            float4 u0 = *(const float4*)(xrow + k0 + q * 8);
            float4 u1 = *(const float4*)(xrow + k0 + q * 8 + 4);
            half8 a;
            a[0] = (_Float16)u0.x; a[1] = (_Float16)u0.y;
            a[2] = (_Float16)u0.z; a[3] = (_Float16)u0.w;
            a[4] = (_Float16)u1.x; a[5] = (_Float16)u1.y;
            a[6] = (_Float16)u1.z; a[7] = (_Float16)u1.w;
            #pragma unroll
            for (int nf = 0; nf < 4; nf++) {
                half8 b = *(const half8*)(wbase + (size_t)nf * 16 * HDIM + k0);
                acc[nf] = __builtin_amdgcn_mfma_f32_16x16x32_f16(a, b, acc[nf], 0, 0, 0);
            }
        }

        #pragma unroll
        for (int nf = 0; nf < 4; nf++)
            #pragma unroll
            for (int i = 0; i < 4; i++)
                part[wv][q * 4 + i][nf * 16 + c] = acc[nf][i];
        __syncthreads();

        #pragma unroll
        for (int j = 0; j < 4; j++) {
            const int idx = tid + 256 * j;
            const int row = idx >> 6, r = idx & 63;
            if (row < nt) {
                const int tok = lists[e * NTOK + base + row];
                float v = part[0][row][r] + part[1][row][r] + part[2][row][r]
                        + part[3][row][r] + b1[e * RDIM + r];
                h[(size_t)tok * RDIM + r] = (_Float16)gelu_exact(v);
            }
        }
        __syncthreads();   // part reused next strip
    }
}

// ---------------------------------------------------------------------------
// mm2 (f16 MFMA, LDS-free, barrier-free): out = (h@w2[e]+b2)*pmax.
// (unchanged this round)
// ---------------------------------------------------------------------------
__global__ __launch_bounds__(256) void mm2_kernel(
    const _Float16* __restrict__ h, const _Float16* __restrict__ w2t,
    const float* __restrict__ b2, const float* __restrict__ pmax,
    const int* __restrict__ counts, const int* __restrict__ lists,
    float* __restrict__ out)
{
    const int e = blockIdx.x;
    const int cnt = counts[e * 32];
    const int wv = threadIdx.x >> 6, lane = threadIdx.x & 63;
    const int q = lane >> 4, c = lane & 15;

    const int task = blockIdx.y * 4 + wv;   // 0..383
    const int nch = task % 3;
    const int sidx = task / 3;              // 0..127

    for (int st = sidx; st * 16 < cnt; st += 128) {
        const int base = st * 16;
        const int nt = cnt - base;
        const int tA = lists[e * NTOK + base + min(c, nt - 1)];
        half8 a0 = *(const half8*)(h + (size_t)tA * RDIM + q * 8);
        half8 a1 = *(const half8*)(h + (size_t)tA * RDIM + 32 + q * 8);

        int tokv[4]; float pm[4]; bool ok[4];
        #pragma unroll
        for (int i = 0; i < 4; i++) {
            const int row = q * 4 + i;
            ok[i] = row < nt;
            tokv[i] = lists[e * NTOK + base + min(row, nt - 1)];
            pm[i] = pmax[tokv[i]];
        }

        #pragma unroll 4
        for (int nf = 0; nf < 16; nf++) {
            const int n = nch * 256 + nf * 16 + c;
            const _Float16* wrow = w2t + ((size_t)(e * HDIM + n)) * RDIM;
            half8 b0 = *(const half8*)(wrow + q * 8);
            half8 b1v = *(const half8*)(wrow + 32 + q * 8);
            float4_t acc = {0, 0, 0, 0};
            acc = __builtin_amdgcn_mfma_f32_16x16x32_f16(a0, b0, acc, 0, 0, 0);
            acc = __builtin_amdgcn_mfma_f32_16x16x32_f16(a1, b1v, acc, 0, 0, 0);
            const float b2v = b2[e * HDIM + n];
            #pragma unroll
            for (int i = 0; i < 4; i++) {
                if (ok[i])
                    out[(size_t)tokv[i] * HDIM + n] = (acc[i] + b2v) * pm[i];
            }
        }
    }
}

extern "C" void kernel_launch(void* const* d_in, const int* in_sizes, int n_in,
                              void* d_out, int out_size, void* d_ws, size_t ws_size,
                              hipStream_t stream) {
    const float* x     = (const float*)d_in[0];
    const float* enc_w = (const float*)d_in[1];
    const float* enc_b = (const float*)d_in[2];
    const float* sw_w  = (const float*)d_in[3];
    const float* sw_b  = (const float*)d_in[4];
    const float* w1    = (const float*)d_in[5];
    const float* b1    = (const float*)d_in[6];
    const float* w2    = (const float*)d_in[7];
    const float* b2    = (const float*)d_in[8];
    float* out = (float*)d_out;

    // ws layout (~4.46 MB):
    //   [0,1K)       counts (8 ints, 128B stride)
    //   [1K,65K)     pmax 16384 f32
    //   [65K,577K)   lists 8*16384 i32
    //   [577K,..)    enc_hi (96K), enc_lo (96K), w1t (768K), w2t (768K), h (2M)
    char* p = (char*)d_ws;
    int*      counts = (int*)p;
    float*    pmax   = (float*)(p + 1024);
    int*      lists  = (int*)(p + 1024 + 65536);
    _Float16* enc_hi = (_Float16*)(p + 590848);
    _Float16* enc_lo = (_Float16*)(p + 590848 + 98304);
    _Float16* w1t    = (_Float16*)(p + 590848 + 196608);
    _Float16* w2t    = (_Float16*)(p + 590848 + 196608 + 786432);
    _Float16* h      = (_Float16*)(p + 590848 + 196608 + 1572864);

    hipMemsetAsync(d_ws, 0, 1024, stream);

    hipLaunchKernelGGL(prep_kernel, dim3(408), dim3(256), 0, stream,
                       w1, w2, enc_w, w1t, w2t, enc_hi, enc_lo);
    hipLaunchKernelGGL(router_kernel, dim3(NTOK / 16), dim3(256), 0, stream,
                       x, enc_hi, enc_lo, enc_b, sw_w, sw_b, pmax, counts, lists);
    hipLaunchKernelGGL(mm1_kernel, dim3(NEXP, 128), dim3(256), 0, stream,
                       x, w1t, b1, counts, lists, h);
    hipLaunchKernelGGL(mm2_kernel, dim3(NEXP, 96), dim3(256), 0, stream,
                       h, w2t, b2, pmax, counts, lists, out);
}

// Round 2
// 195.175 us; speedup vs baseline: 1.1270x; 1.0558x over previous
//
#include <hip/hip_runtime.h>
#include <math.h>

#define HDIM 768
#define RDIM 64
#define NEXP 8
#define NTOK 16384

typedef _Float16 half8 __attribute__((ext_vector_type(8)));
typedef float float4_t __attribute__((ext_vector_type(4)));

__device__ __forceinline__ float gelu_exact(float v) {
    return 0.5f * v * (1.0f + erff(v * 0.70710678118654752440f));
}

// ---------------------------------------------------------------------------
// prep: weight transposes/casts + fused router weight.
//   w1t[e][r][k]  = (f16)w1[e][k][r]
//   w2t[e][n][k]  = (f16)w2[e][k][n]
//   wrt[e][k]     = sum_r enc_w[k][r]*sw_w[r][e]      (fused router, fp32)
//   brr[e]        = sw_b[e] + sum_r enc_b[r]*sw_w[r][e]
// Router is linear before softmax, so the two-stage (enc -> switch) collapses
// into one [768 x 8] matvec. 8x fewer router B-bytes, no hi/lo split needed.
// ---------------------------------------------------------------------------
__global__ __launch_bounds__(256) void prep_kernel(
    const float* __restrict__ w1, const float* __restrict__ w2,
    const float* __restrict__ enc_w, const float* __restrict__ enc_b,
    const float* __restrict__ sw_w, const float* __restrict__ sw_b,
    _Float16* __restrict__ w1t, _Float16* __restrict__ w2t,
    float* __restrict__ wrt, float* __restrict__ brr)
{
    const int wid = blockIdx.x * 4 + (threadIdx.x >> 6);
    const int lane = threadIdx.x & 63;
    if (wid < 768) {
        const int e = wid / 96, k0 = (wid % 96) * 8;
        half8 o;
        #pragma unroll
        for (int j = 0; j < 8; j++)
            o[j] = (_Float16)w1[((size_t)(e * HDIM + k0 + j)) * RDIM + lane];
        *(half8*)(w1t + ((size_t)(e * RDIM + lane)) * HDIM + k0) = o;
    } else if (wid < 1536) {
        const int id = wid - 768;
        const int e = id / 96, rem = id % 96;
        const int n = (rem >> 3) * 64 + lane, k0 = (rem & 7) * 8;
        half8 o;
        #pragma unroll
        for (int j = 0; j < 8; j++)
            o[j] = (_Float16)w2[((size_t)(e * RDIM + k0 + j)) * HDIM + n];
        *(half8*)(w2t + ((size_t)(e * HDIM + n)) * RDIM + k0) = o;
    } else if (wid < 1632) {
        // fused router weight: 8 k-rows per wave, lane = (k_local<<3)|e
        const int k = (wid - 1536) * 8 + (lane >> 3);
        const int e = lane & 7;
        float s = 0.0f;
        #pragma unroll 16
        for (int r = 0; r < RDIM; r++)
            s += enc_w[(size_t)k * RDIM + r] * sw_w[r * NEXP + e];
        wrt[e * HDIM + k] = s;
    } else if (wid == 1632) {
        if (lane < NEXP) {
            float s = sw_b[lane];
            #pragma unroll 16
            for (int r = 0; r < RDIM; r++)
                s += enc_b[r] * sw_w[r * NEXP + lane];
            brr[lane] = s;
        }
    }
}

// ---------------------------------------------------------------------------
// router v3: fused fp32 matvec. Each octet of lanes owns one token;
// lane (oct, e) computes logit[tok][e] directly (no cross-lane K reduce).
// Wr staged in LDS [8][772]: pad 4 words -> octet reads hit 32 disjoint
// banks, broadcast across octets (free). 16 float4 x-loads in flight per
// outer iter (ILP), grid 512 blocks = 2 blocks/CU = 8 waves/CU.
// Epilogue: proven octet-shuffle softmax/argmax + block-aggregated atomics
// (512 serialized adds per expert address, half of v2).
// ---------------------------------------------------------------------------
__global__ __launch_bounds__(256, 4) void router_kernel(
    const float* __restrict__ x, const float* __restrict__ wrt,
    const float* __restrict__ brr, float* __restrict__ pmax,
    int* __restrict__ counts, int* __restrict__ lists)
{
    __shared__ __align__(16) float wrl[NEXP][772];
    __shared__ int lcnt[NEXP], gbase[NEXP];

    const int tid = threadIdx.x;
    // stage Wr (6144 floats = 1536 float4, 6 per thread)
    #pragma unroll
    for (int i0 = 0; i0 < 6; i0++) {
        const int i = tid + i0 * 256;
        const int e = i / 192, k4 = (i % 192) * 4;
        *(float4*)&wrl[e][k4] = *(const float4*)(wrt + e * HDIM + k4);
    }
    if (tid < NEXP) lcnt[tid] = 0;
    __syncthreads();

    const int wv = tid >> 6, lane = tid & 63;
    const int e = lane & 7, tslot = lane >> 3;          // 0..7
    const int tok = blockIdx.x * 32 + wv * 8 + tslot;
    const float* xrow = x + (size_t)tok * HDIM;

    float4_t acc4 = {0.0f, 0.0f, 0.0f, 0.0f};
    for (int k0 = 0; k0 < HDIM; k0 += 64) {
        float4 xv[16];
        #pragma unroll
        for (int u = 0; u < 16; u++)
            xv[u] = *(const float4*)(xrow + k0 + u * 4);
        #pragma unroll
        for (int u = 0; u < 16; u++) {
            const float4 w4 = *(const float4*)(&wrl[e][k0 + u * 4]);
            acc4[0] = fmaf(xv[u].x, w4.x, acc4[0]);
            acc4[1] = fmaf(xv[u].y, w4.y, acc4[1]);
            acc4[2] = fmaf(xv[u].z, w4.z, acc4[2]);
            acc4[3] = fmaf(xv[u].w, w4.w, acc4[3]);
        }
    }
    const float logit = (acc4[0] + acc4[1]) + (acc4[2] + acc4[3]) + brr[e];

    // softmax/argmax over the octet
    float m = logit; int am = e;
    #pragma unroll
    for (int d = 4; d >= 1; d >>= 1) {
        float om = __shfl_xor(m, d, 8);
        int oam  = __shfl_xor(am, d, 8);
        if (om > m || (om == m && oam < am)) { m = om; am = oam; }
    }
    float s = expf(logit - m);
    #pragma unroll
    for (int d = 1; d <= 4; d <<= 1) s += __shfl_xor(s, d, 8);

    int am_s = -1, lp_s = 0;
    if (e == 0) {
        pmax[tok] = 1.0f / s;
        am_s = am;
        lp_s = atomicAdd(&lcnt[am], 1);
    }
    __syncthreads();
    if (tid < NEXP) gbase[tid] = atomicAdd(&counts[tid * 32], lcnt[tid]);
    __syncthreads();
    if (am_s >= 0)
        lists[am_s * NTOK + gbase[am_s] + lp_s] = tok;
}

// ---------------------------------------------------------------------------
// mm1 v3: K-split across 4 waves (as v2) + all 12 x-float4 loads hoisted
// ahead of the convert/MFMA chain (one vmcnt wait per strip instead of 6),
// VGPR cap raised to 128 via launch_bounds(256,4).
// ---------------------------------------------------------------------------
__global__ __launch_bounds__(256, 4) void mm1_kernel(
    const float* __restrict__ x, const _Float16* __restrict__ w1t,
    const float* __restrict__ b1, const int* __restrict__ counts,
    const int* __restrict__ lists, _Float16* __restrict__ h)
{
    __shared__ __align__(16) float part[4][16][68];

    const int e = blockIdx.x;
    const int cnt = counts[e * 32];
    const int tid = threadIdx.x;
    const int wv = tid >> 6, lane = tid & 63;
    const int q = lane >> 4, c = lane & 15;

    for (int st = blockIdx.y; st * 16 < cnt; st += gridDim.y) {
        const int base = st * 16;
        const int nt = cnt - base;
        const int tA = lists[e * NTOK + base + min(c, nt - 1)];
        const float* xrow = x + (size_t)tA * HDIM + wv * 192;
        const _Float16* wbase = w1t + ((size_t)(e * RDIM + c)) * HDIM + wv * 192 + q * 8;

        float4 xv[12];
        #pragma unroll
        for (int it = 0; it < 6; it++) {
            xv[2 * it]     = *(const float4*)(xrow + it * 32 + q * 8);
            xv[2 * it + 1] = *(const float4*)(xrow + it * 32 + q * 8 + 4);
        }

        float4_t acc[4] = {{0,0,0,0},{0,0,0,0},{0,0,0,0},{0,0,0,0}};
        #pragma unroll
        for (int it = 0; it < 6; it++) {
            const int k0 = it * 32;
            half8 a;
            a[0] = (_Float16)xv[2*it].x;   a[1] = (_Float16)xv[2*it].y;
            a[2] = (_Float16)xv[2*it].z;   a[3] = (_Float16)xv[2*it].w;
            a[4] = (_Float16)xv[2*it+1].x; a[5] = (_Float16)xv[2*it+1].y;
            a[6] = (_Float16)xv[2*it+1].z; a[7] = (_Float16)xv[2*it+1].w;
            #pragma unroll
            for (int nf = 0; nf < 4; nf++) {
                half8 b = *(const half8*)(wbase + (size_t)nf * 16 * HDIM + k0);
                acc[nf] = __builtin_amdgcn_mfma_f32_16x16x32_f16(a, b, acc[nf], 0, 0, 0);
            }
        }

        #pragma unroll
        for (int nf = 0; nf < 4; nf++)
            #pragma unroll
            for (int i = 0; i < 4; i++)
                part[wv][q * 4 + i][nf * 16 + c] = acc[nf][i];
        __syncthreads();

        #pragma unroll
        for (int j = 0; j < 4; j++) {
            const int idx = tid + 256 * j;
            const int row = idx >> 6, r = idx & 63;
            if (row < nt) {
                const int tok = lists[e * NTOK + base + row];
                float v = part[0][row][r] + part[1][row][r] + part[2][row][r]
                        + part[3][row][r] + b1[e * RDIM + r];
                h[(size_t)tok * RDIM + r] = (_Float16)gelu_exact(v);
            }
        }
        __syncthreads();   // part reused next strip
    }
}

// ---------------------------------------------------------------------------
// mm2 (f16 MFMA, LDS-free, barrier-free): out = (h@w2[e]+b2)*pmax.
// Only change: VGPR cap raised (grid supplies 3 blocks/CU, so min-3-waves/EU
// costs nothing and gives the scheduler ILP headroom).
// ---------------------------------------------------------------------------
__global__ __launch_bounds__(256, 3) void mm2_kernel(
    const _Float16* __restrict__ h, const _Float16* __restrict__ w2t,
    const float* __restrict__ b2, const float* __restrict__ pmax,
    const int* __restrict__ counts, const int* __restrict__ lists,
    float* __restrict__ out)
{
    const int e = blockIdx.x;
    const int cnt = counts[e * 32];
    const int wv = threadIdx.x >> 6, lane = threadIdx.x & 63;
    const int q = lane >> 4, c = lane & 15;

    const int task = blockIdx.y * 4 + wv;   // 0..383
    const int nch = task % 3;
    const int sidx = task / 3;              // 0..127

    for (int st = sidx; st * 16 < cnt; st += 128) {
        const int base = st * 16;
        const int nt = cnt - base;
        const int tA = lists[e * NTOK + base + min(c, nt - 1)];
        half8 a0 = *(const half8*)(h + (size_t)tA * RDIM + q * 8);
        half8 a1 = *(const half8*)(h + (size_t)tA * RDIM + 32 + q * 8);

        int tokv[4]; float pm[4]; bool ok[4];
        #pragma unroll
        for (int i = 0; i < 4; i++) {
            const int row = q * 4 + i;
            ok[i] = row < nt;
            tokv[i] = lists[e * NTOK + base + min(row, nt - 1)];
            pm[i] = pmax[tokv[i]];
        }

        #pragma unroll 4
        for (int nf = 0; nf < 16; nf++) {
            const int n = nch * 256 + nf * 16 + c;
            const _Float16* wrow = w2t + ((size_t)(e * HDIM + n)) * RDIM;
            half8 b0 = *(const half8*)(wrow + q * 8);
            half8 b1v = *(const half8*)(wrow + 32 + q * 8);
            float4_t acc = {0, 0, 0, 0};
            acc = __builtin_amdgcn_mfma_f32_16x16x32_f16(a0, b0, acc, 0, 0, 0);
            acc = __builtin_amdgcn_mfma_f32_16x16x32_f16(a1, b1v, acc, 0, 0, 0);
            const float b2v = b2[e * HDIM + n];
            #pragma unroll
            for (int i = 0; i < 4; i++) {
                if (ok[i])
                    out[(size_t)tokv[i] * HDIM + n] = (acc[i] + b2v) * pm[i];
            }
        }
    }
}

extern "C" void kernel_launch(void* const* d_in, const int* in_sizes, int n_in,
                              void* d_out, int out_size, void* d_ws, size_t ws_size,
                              hipStream_t stream) {
    const float* x     = (const float*)d_in[0];
    const float* enc_w = (const float*)d_in[1];
    const float* enc_b = (const float*)d_in[2];
    const float* sw_w  = (const float*)d_in[3];
    const float* sw_b  = (const float*)d_in[4];
    const float* w1    = (const float*)d_in[5];
    const float* b1    = (const float*)d_in[6];
    const float* w2    = (const float*)d_in[7];
    const float* b2    = (const float*)d_in[8];
    float* out = (float*)d_out;

    // ws layout (~4.29 MB):
    //   [0,1K)          counts (8 ints, 128B stride)
    //   [1K,65K+1K)     pmax 16384 f32
    //   [66560,590848)  lists 8*16384 i32
    //   [590848,...)    wrt (24K), brr (256B), w1t (768K), w2t (768K), h (2M)
    char* p = (char*)d_ws;
    int*      counts = (int*)p;
    float*    pmax   = (float*)(p + 1024);
    int*      lists  = (int*)(p + 66560);
    float*    wrt    = (float*)(p + 590848);
    float*    brr    = (float*)(p + 615424);
    _Float16* w1t    = (_Float16*)(p + 615680);
    _Float16* w2t    = (_Float16*)(p + 1402112);
    _Float16* h      = (_Float16*)(p + 2188544);

    hipMemsetAsync(d_ws, 0, 1024, stream);

    hipLaunchKernelGGL(prep_kernel, dim3(409), dim3(256), 0, stream,
                       w1, w2, enc_w, enc_b, sw_w, sw_b, w1t, w2t, wrt, brr);
    hipLaunchKernelGGL(router_kernel, dim3(NTOK / 32), dim3(256), 0, stream,
                       x, wrt, brr, pmax, counts, lists);
    hipLaunchKernelGGL(mm1_kernel, dim3(NEXP, 128), dim3(256), 0, stream,
                       x, w1t, b1, counts, lists, h);
    hipLaunchKernelGGL(mm2_kernel, dim3(NEXP, 96), dim3(256), 0, stream,
                       h, w2t, b2, pmax, counts, lists, out);
}

// Round 3
// 194.759 us; speedup vs baseline: 1.1294x; 1.0021x over previous
//
#include <hip/hip_runtime.h>
#include <math.h>

#define HDIM 768
#define RDIM 64
#define NEXP 8
#define NTOK 16384

typedef _Float16 half8 __attribute__((ext_vector_type(8)));
typedef float float4_t __attribute__((ext_vector_type(4)));

__device__ __forceinline__ float gelu_exact(float v) {
    return 0.5f * v * (1.0f + erff(v * 0.70710678118654752440f));
}

// ---------------------------------------------------------------------------
// prep: weight transposes/casts + fused router weight. (unchanged from R2)
//   w1t[e][r][k] = (f16)w1[e][k][r]
//   w2t[e][n][k] = (f16)w2[e][k][n]
//   wrt[e][k]    = sum_r enc_w[k][r]*sw_w[r][e]   (router collapses: linear)
//   brr[e]       = sw_b[e] + sum_r enc_b[r]*sw_w[r][e]
// ---------------------------------------------------------------------------
__global__ __launch_bounds__(256) void prep_kernel(
    const float* __restrict__ w1, const float* __restrict__ w2,
    const float* __restrict__ enc_w, const float* __restrict__ enc_b,
    const float* __restrict__ sw_w, const float* __restrict__ sw_b,
    _Float16* __restrict__ w1t, _Float16* __restrict__ w2t,
    float* __restrict__ wrt, float* __restrict__ brr)
{
    const int wid = blockIdx.x * 4 + (threadIdx.x >> 6);
    const int lane = threadIdx.x & 63;
    if (wid < 768) {
        const int e = wid / 96, k0 = (wid % 96) * 8;
        half8 o;
        #pragma unroll
        for (int j = 0; j < 8; j++)
            o[j] = (_Float16)w1[((size_t)(e * HDIM + k0 + j)) * RDIM + lane];
        *(half8*)(w1t + ((size_t)(e * RDIM + lane)) * HDIM + k0) = o;
    } else if (wid < 1536) {
        const int id = wid - 768;
        const int e = id / 96, rem = id % 96;
        const int n = (rem >> 3) * 64 + lane, k0 = (rem & 7) * 8;
        half8 o;
        #pragma unroll
        for (int j = 0; j < 8; j++)
            o[j] = (_Float16)w2[((size_t)(e * RDIM + k0 + j)) * HDIM + n];
        *(half8*)(w2t + ((size_t)(e * HDIM + n)) * RDIM + k0) = o;
    } else if (wid < 1632) {
        const int k = (wid - 1536) * 8 + (lane >> 3);
        const int e = lane & 7;
        float s = 0.0f;
        #pragma unroll 16
        for (int r = 0; r < RDIM; r++)
            s += enc_w[(size_t)k * RDIM + r] * sw_w[r * NEXP + e];
        wrt[e * HDIM + k] = s;
    } else if (wid == 1632) {
        if (lane < NEXP) {
            float s = sw_b[lane];
            #pragma unroll 16
            for (int r = 0; r < RDIM; r++)
                s += enc_b[r] * sw_w[r * NEXP + lane];
            brr[lane] = s;
        }
    }
}

// ---------------------------------------------------------------------------
// router v4: coalesced split-K matvec.
// Half-wave (32 lanes) per token: lane h loads x[tok][g*128+h*4 .. +3] ->
// every wave-load is 2 contiguous 512B runs (16 fully-used lines/instr),
// vs v3's octet-broadcast gather (128 useful B/instr) which capped at
// ~1.6 TB/s on the L1 transaction rate.
// Weights in LDS wrl[8][772]; per (e,g) read: 32 unique 16B addrs spread
// 4-per-bank-group with half-wave broadcast = LDS peak rate.
// Reduce: 5-level shfl_xor butterfly (stays within 32-lane halves), then
// softmax/argmax entirely in-register; lane h==0 does the routing atomics.
// Grid 1024 blocks x 2 token-iters = 16384 tokens, 4 blocks/CU.
// ---------------------------------------------------------------------------
__global__ __launch_bounds__(256, 4) void router_kernel(
    const float* __restrict__ x, const float* __restrict__ wrt,
    const float* __restrict__ brr, float* __restrict__ pmax,
    int* __restrict__ counts, int* __restrict__ lists)
{
    __shared__ __align__(16) float wrl[NEXP][772];
    __shared__ int lcnt[NEXP], gbase[NEXP];

    const int tid = threadIdx.x;
    #pragma unroll
    for (int i0 = 0; i0 < 6; i0++) {
        const int i = tid + i0 * 256;
        const int e = i / 192, k4 = (i % 192) * 4;
        *(float4*)&wrl[e][k4] = *(const float4*)(wrt + e * HDIM + k4);
    }
    if (tid < NEXP) lcnt[tid] = 0;

    const int wv = tid >> 6, lane = tid & 63;
    const int h = lane & 31, hw = lane >> 5;

    float br[8];
    #pragma unroll
    for (int e = 0; e < 8; e++) br[e] = brr[e];
    __syncthreads();

    int amv[2], lpv[2], tkv[2];
    #pragma unroll
    for (int it = 0; it < 2; it++) {
        const int tok = blockIdx.x * 16 + it * 8 + wv * 2 + hw;
        const float* xrow = x + (size_t)tok * HDIM;
        float4 xv[6];
        #pragma unroll
        for (int g = 0; g < 6; g++)
            xv[g] = *(const float4*)(xrow + g * 128 + h * 4);

        float acc[8];
        #pragma unroll
        for (int e = 0; e < 8; e++) acc[e] = 0.0f;
        #pragma unroll
        for (int e = 0; e < 8; e++) {
            #pragma unroll
            for (int g = 0; g < 6; g++) {
                const float4 w4 = *(const float4*)&wrl[e][g * 128 + h * 4];
                acc[e] = fmaf(xv[g].x, w4.x, acc[e]);
                acc[e] = fmaf(xv[g].y, w4.y, acc[e]);
                acc[e] = fmaf(xv[g].z, w4.z, acc[e]);
                acc[e] = fmaf(xv[g].w, w4.w, acc[e]);
            }
        }
        // butterfly reduce across the 32-lane half (symmetric adds -> all
        // lanes of a half agree bit-exactly)
        #pragma unroll
        for (int d = 1; d < 32; d <<= 1) {
            #pragma unroll
            for (int e = 0; e < 8; e++)
                acc[e] += __shfl_xor(acc[e], d);
        }
        // bias + softmax + argmax in-register (first-max tie-break like ref)
        float lg[8];
        lg[0] = acc[0] + br[0];
        float m = lg[0]; int am = 0;
        #pragma unroll
        for (int e = 1; e < 8; e++) {
            lg[e] = acc[e] + br[e];
            if (lg[e] > m) { m = lg[e]; am = e; }
        }
        float s = 0.0f;
        #pragma unroll
        for (int e = 0; e < 8; e++) s += expf(lg[e] - m);

        amv[it] = -1;
        if (h == 0) {
            pmax[tok] = 1.0f / s;
            amv[it] = am;
            lpv[it] = atomicAdd(&lcnt[am], 1);
            tkv[it] = tok;
        }
    }
    __syncthreads();
    if (tid < NEXP) gbase[tid] = atomicAdd(&counts[tid * 32], lcnt[tid]);
    __syncthreads();
    #pragma unroll
    for (int it = 0; it < 2; it++)
        if (amv[it] >= 0)
            lists[amv[it] * NTOK + gbase[amv[it]] + lpv[it]] = tkv[it];
}

// ---------------------------------------------------------------------------
// mm12 fused: h never leaves LDS.
// Phase A (= old mm1): 16-token strip, K split across 4 waves (192 each,
// 6 k-steps x 4 nf MFMA), partials LDS-reduced, gelu -> hl[16][72] f16
// (pad 72: A-frag read bank-group (9c+q)%8 = optimal).
// Phase B (= old mm2): wave wv covers n in [wv*192, wv*192+192): 12 nf x
// 2 MFMA with A from hl, B = w2t row-gather (L2-resident), epilogue
// (acc+b2)*pmax scatter-store (4 rows x 64B lines per instr).
// Kills: h HBM round-trip, h-gather loads, one launch in the serial chain.
// ---------------------------------------------------------------------------
__global__ __launch_bounds__(256, 4) void mm12_kernel(
    const float* __restrict__ x, const _Float16* __restrict__ w1t,
    const float* __restrict__ b1, const _Float16* __restrict__ w2t,
    const float* __restrict__ b2, const float* __restrict__ pmax,
    const int* __restrict__ counts, const int* __restrict__ lists,
    float* __restrict__ out)
{
    __shared__ __align__(16) float part[4][16][68];
    __shared__ __align__(16) _Float16 hl[16][72];
    __shared__ float pml[16];
    __shared__ int tkl[16];

    const int e = blockIdx.x;
    const int cnt = counts[e * 32];
    const int tid = threadIdx.x;
    const int wv = tid >> 6, lane = tid & 63;
    const int q = lane >> 4, c = lane & 15;

    for (int st = blockIdx.y; st * 16 < cnt; st += gridDim.y) {
        const int base = st * 16;
        const int nt = cnt - base;
        const int tA = lists[e * NTOK + base + min(c, nt - 1)];
        const float* xrow = x + (size_t)tA * HDIM + wv * 192;
        const _Float16* wbase = w1t + ((size_t)(e * RDIM + c)) * HDIM + wv * 192 + q * 8;

        float4 xv[12];
        #pragma unroll
        for (int itk = 0; itk < 6; itk++) {
            xv[2 * itk]     = *(const float4*)(xrow + itk * 32 + q * 8);
            xv[2 * itk + 1] = *(const float4*)(xrow + itk * 32 + q * 8 + 4);
        }

        float4_t acc[4] = {{0,0,0,0},{0,0,0,0},{0,0,0,0},{0,0,0,0}};
        #pragma unroll
        for (int itk = 0; itk < 6; itk++) {
            const int k0 = itk * 32;
            half8 a;
            a[0] = (_Float16)xv[2*itk].x;   a[1] = (_Float16)xv[2*itk].y;
            a[2] = (_Float16)xv[2*itk].z;   a[3] = (_Float16)xv[2*itk].w;
            a[4] = (_Float16)xv[2*itk+1].x; a[5] = (_Float16)xv[2*itk+1].y;
            a[6] = (_Float16)xv[2*itk+1].z; a[7] = (_Float16)xv[2*itk+1].w;
            #pragma unroll
            for (int nf = 0; nf < 4; nf++) {
                half8 b = *(const half8*)(wbase + (size_t)nf * 16 * HDIM + k0);
                acc[nf] = __builtin_amdgcn_mfma_f32_16x16x32_f16(a, b, acc[nf], 0, 0, 0);
            }
        }

        // stage token ids + pmax for the strip epilogue
        if (tid < 16) {
            const int t = lists[e * NTOK + base + min(tid, nt - 1)];
            tkl[tid] = t;
            pml[tid] = pmax[t];
        }

        #pragma unroll
        for (int nf = 0; nf < 4; nf++)
            #pragma unroll
            for (int i = 0; i < 4; i++)
                part[wv][q * 4 + i][nf * 16 + c] = acc[nf][i];
        __syncthreads();

        // reduce 4 K-chunks + bias, gelu, h -> LDS f16
        #pragma unroll
        for (int j = 0; j < 4; j++) {
            const int idx = tid + 256 * j;
            const int row = idx >> 6, r = idx & 63;
            float v = part[0][row][r] + part[1][row][r] + part[2][row][r]
                    + part[3][row][r] + b1[e * RDIM + r];
            hl[row][r] = (_Float16)gelu_exact(v);
        }
        __syncthreads();

        // ---- phase B: out[t][n] for n in wave's 192-col slice ----
        half8 a0 = *(const half8*)&hl[c][q * 8];
        half8 a1 = *(const half8*)&hl[c][32 + q * 8];
        int tokv[4]; float pm[4]; bool ok[4];
        #pragma unroll
        for (int i = 0; i < 4; i++) {
            const int row = q * 4 + i;
            ok[i] = row < nt;
            tokv[i] = tkl[row];
            pm[i] = pml[row];
        }
        #pragma unroll 4
        for (int nf = 0; nf < 12; nf++) {
            const int n = wv * 192 + nf * 16 + c;
            const _Float16* wrow = w2t + ((size_t)(e * HDIM + n)) * RDIM;
            half8 b0  = *(const half8*)(wrow + q * 8);
            half8 b1v = *(const half8*)(wrow + 32 + q * 8);
            float4_t acc2 = {0, 0, 0, 0};
            acc2 = __builtin_amdgcn_mfma_f32_16x16x32_f16(a0, b0, acc2, 0, 0, 0);
            acc2 = __builtin_amdgcn_mfma_f32_16x16x32_f16(a1, b1v, acc2, 0, 0, 0);
            const float b2v = b2[e * HDIM + n];
            #pragma unroll
            for (int i = 0; i < 4; i++) {
                if (ok[i])
                    out[(size_t)tokv[i] * HDIM + n] = (acc2[i] + b2v) * pm[i];
            }
        }
        __syncthreads();   // part/hl reused next strip
    }
}

extern "C" void kernel_launch(void* const* d_in, const int* in_sizes, int n_in,
                              void* d_out, int out_size, void* d_ws, size_t ws_size,
                              hipStream_t stream) {
    const float* x     = (const float*)d_in[0];
    const float* enc_w = (const float*)d_in[1];
    const float* enc_b = (const float*)d_in[2];
    const float* sw_w  = (const float*)d_in[3];
    const float* sw_b  = (const float*)d_in[4];
    const float* w1    = (const float*)d_in[5];
    const float* b1    = (const float*)d_in[6];
    const float* w2    = (const float*)d_in[7];
    const float* b2    = (const float*)d_in[8];
    float* out = (float*)d_out;

    // ws layout (~2.3 MB):
    //   [0,1K)          counts (8 ints, 128B stride)
    //   [1K,66560)      pmax 16384 f32
    //   [66560,590848)  lists 8*16384 i32
    //   [590848,...)    wrt (24K), brr (256B), w1t (768K), w2t (768K)
    char* p = (char*)d_ws;
    int*      counts = (int*)p;
    float*    pmax   = (float*)(p + 1024);
    int*      lists  = (int*)(p + 66560);
    float*    wrt    = (float*)(p + 590848);
    float*    brr    = (float*)(p + 615424);
    _Float16* w1t    = (_Float16*)(p + 615680);
    _Float16* w2t    = (_Float16*)(p + 1402112);

    hipMemsetAsync(d_ws, 0, 1024, stream);

    hipLaunchKernelGGL(prep_kernel, dim3(409), dim3(256), 0, stream,
                       w1, w2, enc_w, enc_b, sw_w, sw_b, w1t, w2t, wrt, brr);
    hipLaunchKernelGGL(router_kernel, dim3(NTOK / 16), dim3(256), 0, stream,
                       x, wrt, brr, pmax, counts, lists);
    hipLaunchKernelGGL(mm12_kernel, dim3(NEXP, 128), dim3(256), 0, stream,
                       x, w1t, b1, w2t, b2, pmax, counts, lists, out);
}